// Round 1
// 228.234 us; speedup vs baseline: 1.0204x; 1.0204x over previous
//
#include <hip/hip_runtime.h>
#include <hip/hip_bf16.h>

typedef unsigned short u16;
typedef __attribute__((ext_vector_type(8))) __bf16 bf16x8;
typedef __attribute__((ext_vector_type(4))) float f32x4;

// Problem dims
#define BB 32
#define LL 512
#define CC 512
#define HH 8
#define DH 64
#define MROWS (BB * LL)        // 16384
#define NQKV  (3 * CC)         // 1536

// workspace layout (bytes)
#define XB_BYTES ((size_t)MROWS * CC * 2)        // 16,777,216  (x bf16; later reused as vT)
#define WC_BYTES ((size_t)NQKV * CC * 2)         //  1,572,864  (wq|wk|wv bf16)
#define QKV_OFF  (XB_BYTES + WC_BYTES)           // qkv bf16: MROWS x 1536

// softmax scale (512^-0.5) * log2(e), folded into wq at cvt time: QK^T MFMA
// output is already in the exp2 domain. No max-subtract needed: scores' std
// ~0.07 (validated R4, absmax unchanged).
#define SCALE2 (0.044194173824159216f * 1.4426950408889634f)

__device__ inline u16 f2b(float f) {
  union { float f; unsigned u; } a; a.f = f;
  unsigned u = a.u;
  return (u16)((u + 0x7FFFu + ((u >> 16) & 1u)) >> 16);
}

__device__ inline unsigned pack2(float a, float b) {  // v_cvt_pk_bf16_f32
  float2 f; f.x = a; f.y = b;
  union { __hip_bfloat162 h; unsigned u; } c;
  c.h = __float22bfloat162_rn(f);
  return c.u;
}

// ---------------- conversion kernels ----------------
__global__ __launch_bounds__(256) void cvt_x(const float* __restrict__ x, u16* __restrict__ xb) {
  int i = blockIdx.x * 256 + threadIdx.x;       // one float4 per thread
  float4 v = ((const float4*)x)[i];
  uint2 o; o.x = pack2(v.x, v.y); o.y = pack2(v.z, v.w);
  ((uint2*)xb)[i] = o;
}

__global__ __launch_bounds__(256) void cvt_w(const float* __restrict__ wq, const float* __restrict__ wk,
                                             const float* __restrict__ wv, u16* __restrict__ wcat) {
  int i = blockIdx.x * 256 + threadIdx.x;       // one float4 per thread
  int e = i * 4;
  int n = e >> 9;                                // output row 0..1535
  int k = e & 511;
  const float* src = (n < 512) ? (wq + (size_t)n * 512)
                   : (n < 1024) ? (wk + (size_t)(n - 512) * 512)
                                : (wv + (size_t)(n - 1024) * 512);
  const float sc = (n < 512) ? SCALE2 : 1.0f;   // fold softmax scale into Q
  float4 v = *(const float4*)(src + k);
  uint2 o; o.x = pack2(v.x * sc, v.y * sc); o.y = pack2(v.z * sc, v.w * sc);
  *(uint2*)(wcat + (size_t)n * 512 + k) = o;
}

// ---------------- async global->LDS ----------------
typedef __attribute__((address_space(1))) void* as1_void_p;
typedef __attribute__((address_space(3))) void* as3_void_p;

__device__ inline void async16(const u16* g, u16* l) {
#if __has_builtin(__builtin_amdgcn_global_load_lds)
  __builtin_amdgcn_global_load_lds((as1_void_p)g, (as3_void_p)l, 16, 0, 0);
#else
  *(uint4*)l = *(const uint4*)g;
#endif
}

// ---------------- QKV projection GEMM (m97-style, unchanged) ----------------
__global__ __launch_bounds__(256) void gemm_qkv(const u16* __restrict__ A, const u16* __restrict__ Bw,
                                                u16* __restrict__ Cm) {
  __shared__ u16 a_lds[128 * 32];
  __shared__ u16 b_lds[128 * 32];
  const int n0 = blockIdx.x * 128, m0 = blockIdx.y * 128;
  const int t = threadIdx.x, l = t & 63;
  const int wrow = ((t >> 7) & 1) * 64, wcol = ((t >> 6) & 1) * 64;
  const int lr = l & 15, lq = l >> 4;

  f32x4 acc[4][4] = {};

  for (int k0 = 0; k0 < 512; k0 += 32) {
    {
      int c0 = t, c1 = t + 256;
      async16(A  + (size_t)(m0 + (c0 >> 2)) * 512 + k0 + (c0 & 3) * 8, &a_lds[c0 * 8]);
      async16(A  + (size_t)(m0 + (c1 >> 2)) * 512 + k0 + (c1 & 3) * 8, &a_lds[c1 * 8]);
      async16(Bw + (size_t)(n0 + (c0 >> 2)) * 512 + k0 + (c0 & 3) * 8, &b_lds[c0 * 8]);
      async16(Bw + (size_t)(n0 + (c1 >> 2)) * 512 + k0 + (c1 & 3) * 8, &b_lds[c1 * 8]);
    }
    __syncthreads();
    bf16x8 af[4], bfr[4];
#pragma unroll
    for (int r = 0; r < 4; ++r) af[r]  = *(const bf16x8*)&a_lds[(wrow + r * 16 + lr) * 32 + lq * 8];
#pragma unroll
    for (int c = 0; c < 4; ++c) bfr[c] = *(const bf16x8*)&b_lds[(wcol + c * 16 + lr) * 32 + lq * 8];
#pragma unroll
    for (int r = 0; r < 4; ++r)
#pragma unroll
      for (int c = 0; c < 4; ++c)
        acc[r][c] = __builtin_amdgcn_mfma_f32_16x16x32_bf16(af[r], bfr[c], acc[r][c], 0, 0, 0);
    __syncthreads();
  }
#pragma unroll
  for (int r = 0; r < 4; ++r) {
#pragma unroll
    for (int i = 0; i < 4; ++i) {
      int m = m0 + wrow + r * 16 + lq * 4 + i;
      u16* crow = Cm + (size_t)m * NQKV + n0 + wcol;
#pragma unroll
      for (int c = 0; c < 4; ++c)
        crow[c * 16 + lr] = f2b(acc[r][c][i]);
    }
  }
}

// ---------------- V transpose: qkv V-part (b,l,h,d) -> vT[(b*8+h)*64+d][l] ----------------
__global__ __launch_bounds__(256) void transpose_v(const u16* __restrict__ qkv, u16* __restrict__ vT) {
  const int bh = blockIdx.x;
  const int b = bh >> 3, h = bh & 7;
  const int lc0 = blockIdx.y * 128;
  __shared__ u16 tile[32 * 72];
  const int t = threadIdx.x;
  for (int lc = lc0; lc < lc0 + 128; lc += 32) {
    int lrow = t >> 3, dcol = (t & 7) * 8;
    const u16* src = qkv + (size_t)(b * 512 + lc + lrow) * NQKV + 1024 + h * 64 + dcol;
    *(uint4*)&tile[lrow * 72 + dcol] = *(const uint4*)src;
    __syncthreads();
    int d = t >> 2, lp = (t & 3) * 8;
    union { ushort4 v4[2]; u16 s[8]; } tmp;
#pragma unroll
    for (int j = 0; j < 8; ++j) tmp.s[j] = tile[(lp + j) * 72 + d];
    *(uint4*)&vT[(size_t)(bh * 64 + d) * 512 + lc + lp] = *(uint4*)&tmp;
    __syncthreads();
  }
}

// ---------------- fused attention (R5: deep-ILP restructure) ----------------
// 256 thr / 4 waves / 32 queries. Wave w owns keys [w*128,+128) in phase 1 and
// d-tile [w*16,+16) in phase 3 (transposed: A=V, B=P -> f32x4 stores).
// No max-subtract; scale folded into wq. 2 barriers total.
// R5: VGPR-starved serialization fix — issue all 16 K loads up front (ak dies
// at the rate sT is born -> flat ~100 live regs), all 16 V loads before
// barrier 2 (latency overlaps pack VALU + barrier convoy), depth-2 pipeline
// on LDS P reads, 4-way exp2 sum accumulators. __launch_bounds__(256,4)
// pins the 128-VGPR budget (occupancy already capped at 16 waves/CU by LDS).
__global__ __launch_bounds__(256, 4) void attn_kernel(const u16* __restrict__ qkv, const u16* __restrict__ vT,
                                                      const float* __restrict__ bias_table,
                                                      float* __restrict__ out) {
  __shared__ u16 p_lds[32 * 512];            // 32 KB
  __shared__ float bias_lds[544];
  __shared__ float reds[4][32];

  const int flat = blockIdx.x;
  const int bh = ((flat >> 7) << 3) | (flat & 7);
  const int q0 = ((flat >> 3) & 15) * 32;
  const int b = bh >> 3, h = bh & 7;
  const int t = threadIdx.x, l = t & 63, w = t >> 6;
  const int lr = l & 15, lq = l >> 4;

  // bias slice: bias for (q,key) = bias_lds[key + 31 - (q - q0)]
  {
    const int rel0 = 480 - q0;
    for (int i = t; i < 543; i += 256)
      bias_lds[i] = bias_table[(size_t)(rel0 + i) * HH + h];
  }

  // Q B-frags (pre-scaled by SCALE2 via cvt_w)
  bf16x8 bq[2][2];
#pragma unroll
  for (int qt = 0; qt < 2; ++qt) {
    const u16* qrow = qkv + (size_t)(b * 512 + q0 + qt * 16 + lr) * NQKV + h * 64;
    bq[qt][0] = *(const bf16x8*)(qrow + lq * 8);
    bq[qt][1] = *(const bf16x8*)(qrow + 32 + lq * 8);
  }

  // ---- phase 1: S^T = K Q^T (already exp2-domain) ----
  // All 16 K loads issued before the MFMA stream: 16 loads in flight, the
  // scheduler drains them with counted vmcnt instead of load->mfma lockstep.
  const u16* kbase = qkv + (size_t)(b * 512 + w * 128 + lr) * NQKV + 512 + h * 64 + lq * 8;
  bf16x8 ak[8][2];
#pragma unroll
  for (int ct = 0; ct < 8; ++ct) {
    const u16* kr = kbase + (size_t)ct * 16 * NQKV;
    ak[ct][0] = *(const bf16x8*)kr;
    ak[ct][1] = *(const bf16x8*)(kr + 32);
  }
  f32x4 sT[2][8];
#pragma unroll
  for (int ct = 0; ct < 8; ++ct) {
    f32x4 a0 = {0.f, 0.f, 0.f, 0.f}, a1 = {0.f, 0.f, 0.f, 0.f};
    a0 = __builtin_amdgcn_mfma_f32_16x16x32_bf16(ak[ct][0], bq[0][0], a0, 0, 0, 0);
    a0 = __builtin_amdgcn_mfma_f32_16x16x32_bf16(ak[ct][1], bq[0][1], a0, 0, 0, 0);
    a1 = __builtin_amdgcn_mfma_f32_16x16x32_bf16(ak[ct][0], bq[1][0], a1, 0, 0, 0);
    a1 = __builtin_amdgcn_mfma_f32_16x16x32_bf16(ak[ct][1], bq[1][1], a1, 0, 0, 0);
    sT[0][ct] = a0;
    sT[1][ct] = a1;
  }

  // exp2 + per-query sum (no max pass); 4 partial accumulators break the
  // 32-long serial add chain.
  float sloc[2];
#pragma unroll
  for (int qt = 0; qt < 2; ++qt) {
    float s0 = 0.f, s1 = 0.f, s2 = 0.f, s3 = 0.f;
#pragma unroll
    for (int ct = 0; ct < 8; ++ct) {
      float e0 = exp2f(sT[qt][ct][0]);
      float e1 = exp2f(sT[qt][ct][1]);
      float e2 = exp2f(sT[qt][ct][2]);
      float e3 = exp2f(sT[qt][ct][3]);
      sT[qt][ct][0] = e0; sT[qt][ct][1] = e1;
      sT[qt][ct][2] = e2; sT[qt][ct][3] = e3;
      s0 += e0; s1 += e1; s2 += e2; s3 += e3;
    }
    float s = (s0 + s1) + (s2 + s3);
    s += __shfl_xor(s, 16, 64);
    s += __shfl_xor(s, 32, 64);
    sloc[qt] = s;
  }
  if (lq == 0) { reds[w][lr] = sloc[0]; reds[w][16 + lr] = sloc[1]; }
  __syncthreads();                                         // barrier 1
  float rinv[2];
#pragma unroll
  for (int qt = 0; qt < 2; ++qt)
    rinv[qt] = 1.0f / (reds[0][qt * 16 + lr] + reds[1][qt * 16 + lr] +
                       reds[2][qt * 16 + lr] + reds[3][qt * 16 + lr]);

  // ---- pack P = e*rinv + bias -> bf16 LDS (swizzled b64 stores) ----
#pragma unroll
  for (int qt = 0; qt < 2; ++qt) {
    const int qlocal = qt * 16 + lr;
    u16* prow = p_lds + qlocal * 512;
    const int boff = w * 128 + lq * 4 + 31 - qlocal;
#pragma unroll
    for (int ct = 0; ct < 8; ++ct) {
      const int gsw = w * 8 + (ct ^ (lr & 7));
      float p0 = sT[qt][ct][0] * rinv[qt] + bias_lds[boff + ct * 16 + 0];
      float p1 = sT[qt][ct][1] * rinv[qt] + bias_lds[boff + ct * 16 + 1];
      float p2 = sT[qt][ct][2] * rinv[qt] + bias_lds[boff + ct * 16 + 2];
      float p3 = sT[qt][ct][3] * rinv[qt] + bias_lds[boff + ct * 16 + 3];
      uint2 pk; pk.x = pack2(p0, p1); pk.y = pack2(p2, p3);
      *(uint2*)&prow[gsw * 16 + lq * 4] = pk;
    }
  }

  // ---- V preload: all 16 loads issued BEFORE barrier 2. Independent of
  // p_lds; their L2 latency overlaps the pack VALU of this wave and the
  // barrier wait on the slowest wave. sT is dead here -> regs are free.
  const u16* vrow = vT + (size_t)(bh * 64 + w * 16 + lr) * 512 + lq * 8;
  bf16x8 av[16];
#pragma unroll
  for (int kb = 0; kb < 16; ++kb) av[kb] = *(const bf16x8*)(vrow + kb * 32);

  __syncthreads();                                         // barrier 2

  // ---- phase 3 (transposed): out^T(d,q) = V^T(d,k) P^T(k,q) ----
  // depth-2 software pipeline on the LDS P reads (ds_read ~120cy latency).
  f32x4 accP[2] = {};
  bf16x8 bpA[2], bpB[2];
#define LDP(kb, qt) \
  (*(const bf16x8*)&p_lds[((qt) * 16 + lr) * 512 + \
    (((2 * (kb) + (lq >> 1)) & ~7) | (((2 * (kb) + (lq >> 1)) & 7) ^ (lr & 7))) * 16 + (lq & 1) * 8])
  bpA[0] = LDP(0, 0);
  bpA[1] = LDP(0, 1);
#pragma unroll
  for (int kb = 0; kb < 16; ++kb) {
    bf16x8 c0, c1;
    if ((kb & 1) == 0) { c0 = bpA[0]; c1 = bpA[1]; }
    else               { c0 = bpB[0]; c1 = bpB[1]; }
    if (kb < 15) {
      if ((kb & 1) == 0) { bpB[0] = LDP(kb + 1, 0); bpB[1] = LDP(kb + 1, 1); }
      else               { bpA[0] = LDP(kb + 1, 0); bpA[1] = LDP(kb + 1, 1); }
    }
    accP[0] = __builtin_amdgcn_mfma_f32_16x16x32_bf16(av[kb], c0, accP[0], 0, 0, 0);
    accP[1] = __builtin_amdgcn_mfma_f32_16x16x32_bf16(av[kb], c1, accP[1], 0, 0, 0);
  }
#undef LDP
  // D[m=d_off][n=q]: lane holds q = lr, d = w*16 + lq*4 + i  -> f32x4 store
#pragma unroll
  for (int qt = 0; qt < 2; ++qt)
    *(f32x4*)&out[(size_t)(b * 512 + q0 + qt * 16 + lr) * 512 + h * 64 + w * 16 + lq * 4] = accP[qt];
}

// ---------------- LayerNorm: 2 rows/block, float4 ----------------
__global__ __launch_bounds__(256) void ln_kernel(float* __restrict__ out,
                                                 const float* __restrict__ gamma,
                                                 const float* __restrict__ beta) {
  const int t = threadIdx.x;
  const int r2 = t >> 7;                       // row half: 0/1
  const int row = blockIdx.x * 2 + r2;
  const int c = (t & 127) * 4;
  float* p = out + (size_t)row * 512;
  float4 v = *(float4*)(p + c);
  float s = v.x + v.y + v.z + v.w;
  float s2 = v.x * v.x + v.y * v.y + v.z * v.z + v.w * v.w;
#pragma unroll
  for (int d = 1; d < 64; d <<= 1) { s += __shfl_xor(s, d, 64); s2 += __shfl_xor(s2, d, 64); }
  __shared__ float ps[4], ps2[4];
  const int wv = t >> 6;
  if ((t & 63) == 0) { ps[wv] = s; ps2[wv] = s2; }
  __syncthreads();
  s  = ps[r2 * 2]  + ps[r2 * 2 + 1];
  s2 = ps2[r2 * 2] + ps2[r2 * 2 + 1];
  float mu = s * (1.0f / 512.0f);
  float var = s2 * (1.0f / 512.0f) - mu * mu;
  float rs = rsqrtf(var + 1e-5f);
  float4 g = *(const float4*)(gamma + c);
  float4 bb = *(const float4*)(beta + c);
  v.x = g.x * (v.x - mu) * rs + bb.x;
  v.y = g.y * (v.y - mu) * rs + bb.y;
  v.z = g.z * (v.z - mu) * rs + bb.z;
  v.w = g.w * (v.w - mu) * rs + bb.w;
  *(float4*)(p + c) = v;
}

extern "C" void kernel_launch(void* const* d_in, const int* in_sizes, int n_in,
                              void* d_out, int out_size, void* d_ws, size_t ws_size,
                              hipStream_t stream) {
  const float* x    = (const float*)d_in[0];
  const float* wq   = (const float*)d_in[1];
  const float* wk   = (const float*)d_in[2];
  const float* wv   = (const float*)d_in[3];
  const float* bias = (const float*)d_in[4];
  const float* gamma = (const float*)d_in[5];
  const float* beta  = (const float*)d_in[6];
  float* out = (float*)d_out;

  char* ws = (char*)d_ws;
  u16* xb   = (u16*)ws;                       // x in bf16 (reused as vT afterwards)
  u16* wcat = (u16*)(ws + XB_BYTES);          // concat weights bf16 (wq pre-scaled)
  u16* qkv  = (u16*)(ws + QKV_OFF);           // MROWS x 1536 bf16
  u16* vT   = xb;                             // reuse: gemm done with xb before transpose

  cvt_x<<<dim3((MROWS * CC) / 4 / 256), 256, 0, stream>>>(x, xb);
  cvt_w<<<dim3((NQKV * CC) / 4 / 256), 256, 0, stream>>>(wq, wk, wv, wcat);
  gemm_qkv<<<dim3(NQKV / 128, MROWS / 128), 256, 0, stream>>>(xb, wcat, qkv);
  transpose_v<<<dim3(256, 4), 256, 0, stream>>>(qkv, vT);
  attn_kernel<<<dim3(16 * 256), 256, 0, stream>>>(qkv, vT, bias, out);
  ln_kernel<<<dim3(MROWS / 2), 256, 0, stream>>>(out, gamma, beta);
}

// Round 2
// 227.788 us; speedup vs baseline: 1.0224x; 1.0020x over previous
//
#include <hip/hip_runtime.h>
#include <hip/hip_bf16.h>

typedef unsigned short u16;
typedef __attribute__((ext_vector_type(8))) __bf16 bf16x8;
typedef __attribute__((ext_vector_type(4))) float f32x4;
typedef __attribute__((ext_vector_type(4))) unsigned int u32x4;

// Problem dims
#define BB 32
#define LL 512
#define CC 512
#define HH 8
#define DH 64
#define MROWS (BB * LL)        // 16384
#define NQKV  (3 * CC)         // 1536

// workspace layout (bytes)
#define XB_BYTES ((size_t)MROWS * CC * 2)        // 16,777,216  (x bf16; later reused as vT)
#define WC_BYTES ((size_t)NQKV * CC * 2)         //  1,572,864  (wq|wk|wv bf16; dead after gemm -> biasT)
#define QKV_OFF  (XB_BYTES + WC_BYTES)           // qkv bf16: MROWS x 1536

// softmax scale (512^-0.5) * log2(e), folded into wq at cvt time: QK^T MFMA
// output is already in the exp2 domain. No max-subtract needed: scores' std
// ~0.07 (validated R4, absmax unchanged).
#define SCALE2 (0.044194173824159216f * 1.4426950408889634f)

__device__ inline u16 f2b(float f) {
  union { float f; unsigned u; } a; a.f = f;
  unsigned u = a.u;
  return (u16)((u + 0x7FFFu + ((u >> 16) & 1u)) >> 16);
}

__device__ inline unsigned pack2(float a, float b) {  // v_cvt_pk_bf16_f32
  float2 f; f.x = a; f.y = b;
  union { __hip_bfloat162 h; unsigned u; } c;
  c.h = __float22bfloat162_rn(f);
  return c.u;
}

// Forced 16B global load: volatile asm so hipcc can NOT sink it into the
// consuming loop (R5 post-mortem: ordinary preloads were re-serialized,
// VGPR dropped to 60). Consumers get a data dep on the output regs; the
// vmcnt wait is inserted manually (rule #18: + sched_barrier after it).
__device__ inline bf16x8 gload16(const u16* p) {
  u32x4 r;
  asm volatile("global_load_dwordx4 %0, %1, off" : "=v"(r) : "v"(p));
  return __builtin_bit_cast(bf16x8, r);
}

// ---------------- conversion kernels ----------------
__global__ __launch_bounds__(256) void cvt_x(const float* __restrict__ x, u16* __restrict__ xb) {
  int i = blockIdx.x * 256 + threadIdx.x;       // one float4 per thread
  float4 v = ((const float4*)x)[i];
  uint2 o; o.x = pack2(v.x, v.y); o.y = pack2(v.z, v.w);
  ((uint2*)xb)[i] = o;
}

__global__ __launch_bounds__(256) void cvt_w(const float* __restrict__ wq, const float* __restrict__ wk,
                                             const float* __restrict__ wv, u16* __restrict__ wcat) {
  int i = blockIdx.x * 256 + threadIdx.x;       // one float4 per thread
  int e = i * 4;
  int n = e >> 9;                                // output row 0..1535
  int k = e & 511;
  const float* src = (n < 512) ? (wq + (size_t)n * 512)
                   : (n < 1024) ? (wk + (size_t)(n - 512) * 512)
                                : (wv + (size_t)(n - 1024) * 512);
  const float sc = (n < 512) ? SCALE2 : 1.0f;   // fold softmax scale into Q
  float4 v = *(const float4*)(src + k);
  uint2 o; o.x = pack2(v.x * sc, v.y * sc); o.y = pack2(v.z * sc, v.w * sc);
  *(uint2*)(wcat + (size_t)n * 512 + k) = o;
}

// bias table transpose: bias_table[rel][h] -> biasT[h][rel] (f32, 1024 pad).
// Makes the per-attn-block bias slice fill a coalesced read instead of 543
// stride-32B gathers. Lives in the dead wcat region (no ws growth).
__global__ __launch_bounds__(256) void bias_trans(const float* __restrict__ bias_table,
                                                  float* __restrict__ biasT) {
  int i = blockIdx.x * 256 + threadIdx.x;       // coalesced read of 1023*8
  if (i < 1023 * 8) {
    float v = bias_table[i];
    int rel = i >> 3, hh = i & 7;
    biasT[hh * 1024 + rel] = v;
  }
}

// ---------------- async global->LDS ----------------
typedef __attribute__((address_space(1))) void* as1_void_p;
typedef __attribute__((address_space(3))) void* as3_void_p;

__device__ inline void async16(const u16* g, u16* l) {
#if __has_builtin(__builtin_amdgcn_global_load_lds)
  __builtin_amdgcn_global_load_lds((as1_void_p)g, (as3_void_p)l, 16, 0, 0);
#else
  *(uint4*)l = *(const uint4*)g;
#endif
}

// ---------------- QKV projection GEMM (m97-style, unchanged) ----------------
__global__ __launch_bounds__(256) void gemm_qkv(const u16* __restrict__ A, const u16* __restrict__ Bw,
                                                u16* __restrict__ Cm) {
  __shared__ u16 a_lds[128 * 32];
  __shared__ u16 b_lds[128 * 32];
  const int n0 = blockIdx.x * 128, m0 = blockIdx.y * 128;
  const int t = threadIdx.x, l = t & 63;
  const int wrow = ((t >> 7) & 1) * 64, wcol = ((t >> 6) & 1) * 64;
  const int lr = l & 15, lq = l >> 4;

  f32x4 acc[4][4] = {};

  for (int k0 = 0; k0 < 512; k0 += 32) {
    {
      int c0 = t, c1 = t + 256;
      async16(A  + (size_t)(m0 + (c0 >> 2)) * 512 + k0 + (c0 & 3) * 8, &a_lds[c0 * 8]);
      async16(A  + (size_t)(m0 + (c1 >> 2)) * 512 + k0 + (c1 & 3) * 8, &a_lds[c1 * 8]);
      async16(Bw + (size_t)(n0 + (c0 >> 2)) * 512 + k0 + (c0 & 3) * 8, &b_lds[c0 * 8]);
      async16(Bw + (size_t)(n0 + (c1 >> 2)) * 512 + k0 + (c1 & 3) * 8, &b_lds[c1 * 8]);
    }
    __syncthreads();
    bf16x8 af[4], bfr[4];
#pragma unroll
    for (int r = 0; r < 4; ++r) af[r]  = *(const bf16x8*)&a_lds[(wrow + r * 16 + lr) * 32 + lq * 8];
#pragma unroll
    for (int c = 0; c < 4; ++c) bfr[c] = *(const bf16x8*)&b_lds[(wcol + c * 16 + lr) * 32 + lq * 8];
#pragma unroll
    for (int r = 0; r < 4; ++r)
#pragma unroll
      for (int c = 0; c < 4; ++c)
        acc[r][c] = __builtin_amdgcn_mfma_f32_16x16x32_bf16(af[r], bfr[c], acc[r][c], 0, 0, 0);
    __syncthreads();
  }
#pragma unroll
  for (int r = 0; r < 4; ++r) {
#pragma unroll
    for (int i = 0; i < 4; ++i) {
      int m = m0 + wrow + r * 16 + lq * 4 + i;
      u16* crow = Cm + (size_t)m * NQKV + n0 + wcol;
#pragma unroll
      for (int c = 0; c < 4; ++c)
        crow[c * 16 + lr] = f2b(acc[r][c][i]);
    }
  }
}

// ---------------- V transpose: qkv V-part (b,l,h,d) -> vT[(b*8+h)*64+d][l] ----------------
__global__ __launch_bounds__(256) void transpose_v(const u16* __restrict__ qkv, u16* __restrict__ vT) {
  const int bh = blockIdx.x;
  const int b = bh >> 3, h = bh & 7;
  const int lc0 = blockIdx.y * 128;
  __shared__ u16 tile[32 * 72];
  const int t = threadIdx.x;
  for (int lc = lc0; lc < lc0 + 128; lc += 32) {
    int lrow = t >> 3, dcol = (t & 7) * 8;
    const u16* src = qkv + (size_t)(b * 512 + lc + lrow) * NQKV + 1024 + h * 64 + dcol;
    *(uint4*)&tile[lrow * 72 + dcol] = *(const uint4*)src;
    __syncthreads();
    int d = t >> 2, lp = (t & 3) * 8;
    union { ushort4 v4[2]; u16 s[8]; } tmp;
#pragma unroll
    for (int j = 0; j < 8; ++j) tmp.s[j] = tile[(lp + j) * 72 + d];
    *(uint4*)&vT[(size_t)(bh * 64 + d) * 512 + lc + lp] = *(uint4*)&tmp;
    __syncthreads();
  }
}

// ---------------- fused attention (R6: asm-pinned preloads) ----------------
// 256 thr / 4 waves / 32 queries. Wave w owns keys [w*128,+128) in phase 1 and
// d-tile [w*16,+16) in phase 3 (transposed: A=V, B=P -> f32x4 stores).
// R6: K and V preloads are volatile-asm global_load_dwordx4 (compiler cannot
// sink them — R5 showed it re-serialized ordinary preloads, VGPR 60). V loads
// issue between barrier 1 and the pack loop, split 8+8 around qt=0's pack to
// keep peak VGPR ~115 < 128; barrier 2's vmcnt(0) drain completes them free.
// PV LDS P reads pipelined depth-4 (static slot indices). Bias slice fill is
// coalesced from biasT.
__global__ __launch_bounds__(256, 4) void attn_kernel(const u16* __restrict__ qkv, const u16* __restrict__ vT,
                                                      const float* __restrict__ biasT,
                                                      float* __restrict__ out) {
  __shared__ u16 p_lds[32 * 512];            // 32 KB
  __shared__ float bias_lds[544];
  __shared__ float reds[4][32];

  const int flat = blockIdx.x;
  const int bh = ((flat >> 7) << 3) | (flat & 7);
  const int q0 = ((flat >> 3) & 15) * 32;
  const int b = bh >> 3, h = bh & 7;
  const int t = threadIdx.x, l = t & 63, w = t >> 6;
  const int lr = l & 15, lq = l >> 4;

  // bias slice (coalesced): bias for (q,key) = bias_lds[key + 31 - (q - q0)]
  {
    const int rel0 = 480 - q0;
    const float* bsrc = biasT + h * 1024 + rel0;
    for (int i = t; i < 543; i += 256)
      bias_lds[i] = bsrc[i];
  }

  // Q B-frags (pre-scaled by SCALE2 via cvt_w)
  bf16x8 bq[2][2];
#pragma unroll
  for (int qt = 0; qt < 2; ++qt) {
    const u16* qrow = qkv + (size_t)(b * 512 + q0 + qt * 16 + lr) * NQKV + h * 64;
    bq[qt][0] = *(const bf16x8*)(qrow + lq * 8);
    bq[qt][1] = *(const bf16x8*)(qrow + 32 + lq * 8);
  }

  // ---- phase 1: S^T = K Q^T (already exp2-domain) ----
  // All 16 K loads issued as pinned asm; single drain; then pure-reg MFMAs.
  const u16* kbase = qkv + (size_t)(b * 512 + w * 128 + lr) * NQKV + 512 + h * 64 + lq * 8;
  bf16x8 ak[8][2];
#pragma unroll
  for (int ct = 0; ct < 8; ++ct) {
    const u16* kr = kbase + (size_t)ct * 16 * NQKV;
    ak[ct][0] = gload16(kr);
    ak[ct][1] = gload16(kr + 32);
  }
  asm volatile("s_waitcnt vmcnt(0)" ::: "memory");
  __builtin_amdgcn_sched_barrier(0);           // rule #18: pin MFMAs after wait

  f32x4 sT[2][8];
#pragma unroll
  for (int ct = 0; ct < 8; ++ct) {
    f32x4 a0 = {0.f, 0.f, 0.f, 0.f}, a1 = {0.f, 0.f, 0.f, 0.f};
    a0 = __builtin_amdgcn_mfma_f32_16x16x32_bf16(ak[ct][0], bq[0][0], a0, 0, 0, 0);
    a0 = __builtin_amdgcn_mfma_f32_16x16x32_bf16(ak[ct][1], bq[0][1], a0, 0, 0, 0);
    a1 = __builtin_amdgcn_mfma_f32_16x16x32_bf16(ak[ct][0], bq[1][0], a1, 0, 0, 0);
    a1 = __builtin_amdgcn_mfma_f32_16x16x32_bf16(ak[ct][1], bq[1][1], a1, 0, 0, 0);
    sT[0][ct] = a0;
    sT[1][ct] = a1;
  }

  // exp2 + per-query sum (no max pass); 4 partial accumulators.
  float sloc[2];
#pragma unroll
  for (int qt = 0; qt < 2; ++qt) {
    float s0 = 0.f, s1 = 0.f, s2 = 0.f, s3 = 0.f;
#pragma unroll
    for (int ct = 0; ct < 8; ++ct) {
      float e0 = exp2f(sT[qt][ct][0]);
      float e1 = exp2f(sT[qt][ct][1]);
      float e2 = exp2f(sT[qt][ct][2]);
      float e3 = exp2f(sT[qt][ct][3]);
      sT[qt][ct][0] = e0; sT[qt][ct][1] = e1;
      sT[qt][ct][2] = e2; sT[qt][ct][3] = e3;
      s0 += e0; s1 += e1; s2 += e2; s3 += e3;
    }
    float s = (s0 + s1) + (s2 + s3);
    s += __shfl_xor(s, 16, 64);
    s += __shfl_xor(s, 32, 64);
    sloc[qt] = s;
  }
  if (lq == 0) { reds[w][lr] = sloc[0]; reds[w][16 + lr] = sloc[1]; }
  __syncthreads();                                         // barrier 1
  float rinv[2];
#pragma unroll
  for (int qt = 0; qt < 2; ++qt)
    rinv[qt] = 1.0f / (reds[0][qt * 16 + lr] + reds[1][qt * 16 + lr] +
                       reds[2][qt * 16 + lr] + reds[3][qt * 16 + lr]);

  // ---- V preload (pinned asm), split 8+8 around the qt=0 pack so peak
  // VGPR stays under 128. Latency hides under pack VALU/DS + barrier 2.
  const u16* vrow = vT + (size_t)(bh * 64 + w * 16 + lr) * 512 + lq * 8;
  bf16x8 av[16];
#pragma unroll
  for (int kb = 0; kb < 8; ++kb) av[kb] = gload16(vrow + kb * 32);

  // ---- pack P = e*rinv + bias -> bf16 LDS (swizzled b64 stores) ----
#define PACK_QT(qt)                                                            \
  {                                                                            \
    const int qlocal = (qt) * 16 + lr;                                         \
    u16* prow = p_lds + qlocal * 512;                                          \
    const int boff = w * 128 + lq * 4 + 31 - qlocal;                           \
    _Pragma("unroll")                                                          \
    for (int ct = 0; ct < 8; ++ct) {                                           \
      const int gsw = w * 8 + (ct ^ (lr & 7));                                 \
      float p0 = sT[qt][ct][0] * rinv[qt] + bias_lds[boff + ct * 16 + 0];      \
      float p1 = sT[qt][ct][1] * rinv[qt] + bias_lds[boff + ct * 16 + 1];      \
      float p2 = sT[qt][ct][2] * rinv[qt] + bias_lds[boff + ct * 16 + 2];      \
      float p3 = sT[qt][ct][3] * rinv[qt] + bias_lds[boff + ct * 16 + 3];      \
      uint2 pk; pk.x = pack2(p0, p1); pk.y = pack2(p2, p3);                    \
      *(uint2*)&prow[gsw * 16 + lq * 4] = pk;                                  \
    }                                                                          \
  }

  PACK_QT(0)
#pragma unroll
  for (int kb = 8; kb < 16; ++kb) av[kb] = gload16(vrow + kb * 32);
  PACK_QT(1)
#undef PACK_QT

  __syncthreads();                                         // barrier 2 (drains vmcnt)
  asm volatile("s_waitcnt vmcnt(0)" ::: "memory");         // belt + suspenders
  __builtin_amdgcn_sched_barrier(0);

  // ---- phase 3 (transposed): out^T(d,q) = V^T(d,k) P^T(k,q) ----
  // depth-4 software pipeline on the LDS P reads (ds_read ~120cy latency).
  f32x4 accP[2] = {};
  bf16x8 bp[4][2];
#define LDP(kb, qt) \
  (*(const bf16x8*)&p_lds[((qt) * 16 + lr) * 512 + \
    (((2 * (kb) + (lq >> 1)) & ~7) | (((2 * (kb) + (lq >> 1)) & 7) ^ (lr & 7))) * 16 + (lq & 1) * 8])
#pragma unroll
  for (int pre = 0; pre < 3; ++pre) { bp[pre][0] = LDP(pre, 0); bp[pre][1] = LDP(pre, 1); }
#pragma unroll
  for (int kb = 0; kb < 16; ++kb) {
    if (kb < 13) {
      bp[(kb + 3) & 3][0] = LDP(kb + 3, 0);
      bp[(kb + 3) & 3][1] = LDP(kb + 3, 1);
    }
    accP[0] = __builtin_amdgcn_mfma_f32_16x16x32_bf16(av[kb], bp[kb & 3][0], accP[0], 0, 0, 0);
    accP[1] = __builtin_amdgcn_mfma_f32_16x16x32_bf16(av[kb], bp[kb & 3][1], accP[1], 0, 0, 0);
  }
#undef LDP
  // D[m=d_off][n=q]: lane holds q = lr, d = w*16 + lq*4 + i  -> f32x4 store
#pragma unroll
  for (int qt = 0; qt < 2; ++qt)
    *(f32x4*)&out[(size_t)(b * 512 + q0 + qt * 16 + lr) * 512 + h * 64 + w * 16 + lq * 4] = accP[qt];
}

// ---------------- LayerNorm: 2 rows/block, float4 ----------------
__global__ __launch_bounds__(256) void ln_kernel(float* __restrict__ out,
                                                 const float* __restrict__ gamma,
                                                 const float* __restrict__ beta) {
  const int t = threadIdx.x;
  const int r2 = t >> 7;                       // row half: 0/1
  const int row = blockIdx.x * 2 + r2;
  const int c = (t & 127) * 4;
  float* p = out + (size_t)row * 512;
  float4 v = *(float4*)(p + c);
  float s = v.x + v.y + v.z + v.w;
  float s2 = v.x * v.x + v.y * v.y + v.z * v.z + v.w * v.w;
#pragma unroll
  for (int d = 1; d < 64; d <<= 1) { s += __shfl_xor(s, d, 64); s2 += __shfl_xor(s2, d, 64); }
  __shared__ float ps[4], ps2[4];
  const int wv = t >> 6;
  if ((t & 63) == 0) { ps[wv] = s; ps2[wv] = s2; }
  __syncthreads();
  s  = ps[r2 * 2]  + ps[r2 * 2 + 1];
  s2 = ps2[r2 * 2] + ps2[r2 * 2 + 1];
  float mu = s * (1.0f / 512.0f);
  float var = s2 * (1.0f / 512.0f) - mu * mu;
  float rs = rsqrtf(var + 1e-5f);
  float4 g = *(const float4*)(gamma + c);
  float4 bb = *(const float4*)(beta + c);
  v.x = g.x * (v.x - mu) * rs + bb.x;
  v.y = g.y * (v.y - mu) * rs + bb.y;
  v.z = g.z * (v.z - mu) * rs + bb.z;
  v.w = g.w * (v.w - mu) * rs + bb.w;
  *(float4*)(p + c) = v;
}

extern "C" void kernel_launch(void* const* d_in, const int* in_sizes, int n_in,
                              void* d_out, int out_size, void* d_ws, size_t ws_size,
                              hipStream_t stream) {
  const float* x    = (const float*)d_in[0];
  const float* wq   = (const float*)d_in[1];
  const float* wk   = (const float*)d_in[2];
  const float* wv   = (const float*)d_in[3];
  const float* bias = (const float*)d_in[4];
  const float* gamma = (const float*)d_in[5];
  const float* beta  = (const float*)d_in[6];
  float* out = (float*)d_out;

  char* ws = (char*)d_ws;
  u16* xb   = (u16*)ws;                       // x in bf16 (reused as vT afterwards)
  u16* wcat = (u16*)(ws + XB_BYTES);          // concat weights bf16 (wq pre-scaled)
  u16* qkv  = (u16*)(ws + QKV_OFF);           // MROWS x 1536 bf16
  u16* vT   = xb;                             // reuse: gemm done with xb before transpose
  float* biasT = (float*)(ws + XB_BYTES);     // reuse wcat region after gemm (8 x 1024 f32)

  cvt_x<<<dim3((MROWS * CC) / 4 / 256), 256, 0, stream>>>(x, xb);
  cvt_w<<<dim3((NQKV * CC) / 4 / 256), 256, 0, stream>>>(wq, wk, wv, wcat);
  gemm_qkv<<<dim3(NQKV / 128, MROWS / 128), 256, 0, stream>>>(xb, wcat, qkv);
  bias_trans<<<dim3(32), 256, 0, stream>>>(bias, biasT);
  transpose_v<<<dim3(256, 4), 256, 0, stream>>>(qkv, vT);
  attn_kernel<<<dim3(16 * 256), 256, 0, stream>>>(qkv, vT, biasT, out);
  ln_kernel<<<dim3(MROWS / 2), 256, 0, stream>>>(out, gamma, beta);
}

// Round 4
// 227.001 us; speedup vs baseline: 1.0260x; 1.0035x over previous
//
#include <hip/hip_runtime.h>
#include <hip/hip_bf16.h>

typedef unsigned short u16;
typedef __attribute__((ext_vector_type(8))) __bf16 bf16x8;
typedef __attribute__((ext_vector_type(4))) float f32x4;
typedef __attribute__((ext_vector_type(4))) unsigned int u32x4;

// Problem dims
#define BB 32
#define LL 512
#define CC 512
#define HH 8
#define DH 64
#define MROWS (BB * LL)        // 16384
#define NQKV  (3 * CC)         // 1536

// workspace layout (bytes)
#define XB_BYTES ((size_t)MROWS * CC * 2)        // 16,777,216  (x bf16; later reused as vT)
#define WC_BYTES ((size_t)NQKV * CC * 2)         //  1,572,864  (wq|wk|wv bf16; dead after gemm -> biasT)
#define QKV_OFF  (XB_BYTES + WC_BYTES)           // qkv bf16: MROWS x 1536

// softmax scale (512^-0.5) * log2(e), folded into wq at cvt time: QK^T MFMA
// output is already in the exp2 domain. No max-subtract needed (scores' std
// ~0.07, validated R4).
#define SCALE2 (0.044194173824159216f * 1.4426950408889634f)

__device__ inline u16 f2b(float f) {
  union { float f; unsigned u; } a; a.f = f;
  unsigned u = a.u;
  return (u16)((u + 0x7FFFu + ((u >> 16) & 1u)) >> 16);
}

__device__ inline unsigned pack2(float a, float b) {  // v_cvt_pk_bf16_f32
  float2 f; f.x = a; f.y = b;
  union { __hip_bfloat162 h; unsigned u; } c;
  c.h = __float22bfloat162_rn(f);
  return c.u;
}

// ---------------- conversion kernels ----------------
__global__ __launch_bounds__(256) void cvt_x(const float* __restrict__ x, u16* __restrict__ xb) {
  int i = blockIdx.x * 256 + threadIdx.x;       // one float4 per thread
  float4 v = ((const float4*)x)[i];
  uint2 o; o.x = pack2(v.x, v.y); o.y = pack2(v.z, v.w);
  ((uint2*)xb)[i] = o;
}

__global__ __launch_bounds__(256) void cvt_w(const float* __restrict__ wq, const float* __restrict__ wk,
                                             const float* __restrict__ wv, u16* __restrict__ wcat) {
  int i = blockIdx.x * 256 + threadIdx.x;       // one float4 per thread
  int e = i * 4;
  int n = e >> 9;                                // output row 0..1535
  int k = e & 511;
  const float* src = (n < 512) ? (wq + (size_t)n * 512)
                   : (n < 1024) ? (wk + (size_t)(n - 512) * 512)
                                : (wv + (size_t)(n - 1024) * 512);
  const float sc = (n < 512) ? SCALE2 : 1.0f;   // fold softmax scale into Q
  float4 v = *(const float4*)(src + k);
  uint2 o; o.x = pack2(v.x * sc, v.y * sc); o.y = pack2(v.z * sc, v.w * sc);
  *(uint2*)(wcat + (size_t)n * 512 + k) = o;
}

// ---------------- async global->LDS ----------------
typedef __attribute__((address_space(1))) void* as1_void_p;
typedef __attribute__((address_space(3))) void* as3_void_p;

__device__ inline void async16(const u16* g, u16* l) {
#if __has_builtin(__builtin_amdgcn_global_load_lds)
  __builtin_amdgcn_global_load_lds((as1_void_p)g, (as3_void_p)l, 16, 0, 0);
#else
  *(uint4*)l = *(const uint4*)g;
#endif
}

// ---------------- QKV projection GEMM (m97-style, unchanged) ----------------
__global__ __launch_bounds__(256) void gemm_qkv(const u16* __restrict__ A, const u16* __restrict__ Bw,
                                                u16* __restrict__ Cm) {
  __shared__ u16 a_lds[128 * 32];
  __shared__ u16 b_lds[128 * 32];
  const int n0 = blockIdx.x * 128, m0 = blockIdx.y * 128;
  const int t = threadIdx.x, l = t & 63;
  const int wrow = ((t >> 7) & 1) * 64, wcol = ((t >> 6) & 1) * 64;
  const int lr = l & 15, lq = l >> 4;

  f32x4 acc[4][4] = {};

  for (int k0 = 0; k0 < 512; k0 += 32) {
    {
      int c0 = t, c1 = t + 256;
      async16(A  + (size_t)(m0 + (c0 >> 2)) * 512 + k0 + (c0 & 3) * 8, &a_lds[c0 * 8]);
      async16(A  + (size_t)(m0 + (c1 >> 2)) * 512 + k0 + (c1 & 3) * 8, &a_lds[c1 * 8]);
      async16(Bw + (size_t)(n0 + (c0 >> 2)) * 512 + k0 + (c0 & 3) * 8, &b_lds[c0 * 8]);
      async16(Bw + (size_t)(n0 + (c1 >> 2)) * 512 + k0 + (c1 & 3) * 8, &b_lds[c1 * 8]);
    }
    __syncthreads();
    bf16x8 af[4], bfr[4];
#pragma unroll
    for (int r = 0; r < 4; ++r) af[r]  = *(const bf16x8*)&a_lds[(wrow + r * 16 + lr) * 32 + lq * 8];
#pragma unroll
    for (int c = 0; c < 4; ++c) bfr[c] = *(const bf16x8*)&b_lds[(wcol + c * 16 + lr) * 32 + lq * 8];
#pragma unroll
    for (int r = 0; r < 4; ++r)
#pragma unroll
      for (int c = 0; c < 4; ++c)
        acc[r][c] = __builtin_amdgcn_mfma_f32_16x16x32_bf16(af[r], bfr[c], acc[r][c], 0, 0, 0);
    __syncthreads();
  }
#pragma unroll
  for (int r = 0; r < 4; ++r) {
#pragma unroll
    for (int i = 0; i < 4; ++i) {
      int m = m0 + wrow + r * 16 + lq * 4 + i;
      u16* crow = Cm + (size_t)m * NQKV + n0 + wcol;
#pragma unroll
      for (int c = 0; c < 4; ++c)
        crow[c * 16 + lr] = f2b(acc[r][c][i]);
    }
  }
}

// ---------------- V transpose + bias transpose ----------------
// blockIdx.y < 4 : qkv V-part (b,l,h,d) -> vT[(b*8+h)*64+d][l]
// blockIdx.y == 4: bias_table[rel][h] -> biasT[h][rel] (only x<32 active)
__global__ __launch_bounds__(256) void transpose_v(const u16* __restrict__ qkv, u16* __restrict__ vT,
                                                   const float* __restrict__ bias_table,
                                                   float* __restrict__ biasT) {
  if (blockIdx.y == 4) {
    if (blockIdx.x < 32) {
      int i = blockIdx.x * 256 + threadIdx.x;   // coalesced read of 1023*8
      if (i < 1023 * 8) {
        float v = bias_table[i];
        int rel = i >> 3, hh = i & 7;
        biasT[hh * 1024 + rel] = v;
      }
    }
    return;
  }
  const int bh = blockIdx.x;
  const int b = bh >> 3, h = bh & 7;
  const int lc0 = blockIdx.y * 128;
  __shared__ u16 tile[32 * 72];
  const int t = threadIdx.x;
  for (int lc = lc0; lc < lc0 + 128; lc += 32) {
    int lrow = t >> 3, dcol = (t & 7) * 8;
    const u16* src = qkv + (size_t)(b * 512 + lc + lrow) * NQKV + 1024 + h * 64 + dcol;
    *(uint4*)&tile[lrow * 72 + dcol] = *(const uint4*)src;
    __syncthreads();
    int d = t >> 2, lp = (t & 3) * 8;
    union { ushort4 v4[2]; u16 s[8]; } tmp;
#pragma unroll
    for (int j = 0; j < 8; ++j) tmp.s[j] = tile[(lp + j) * 72 + d];
    *(uint4*)&vT[(size_t)(bh * 64 + d) * 512 + lc + lp] = *(uint4*)&tmp;
    __syncthreads();
  }
}

// ---------------- fused attention (R8: R7 + early-clobber asm fix) ----------
// 256 thr / 4 waves / 32 queries. Wave w owns keys [w*128,+128) in phase 1 and
// d-tile [w*16,+16) in phase 3 (transposed: A=V, B=P -> f32x4 stores).
// R8: R7 crashed — paired-load asm without early-clobber let outputs alias the
// address VGPR pair (async write-back corrupts addr of 2nd load). All asm load
// outputs are now "=&v". Otherwise identical to R7: launch_bounds(256,3) frees
// ~170 arch VGPRs (occupancy LDS-capped at 3 blocks/CU anyway) so sT lives in
// arch VGPRs, no v_accvgpr ping-pong (R6: VGPR=64, inflated VALUBusy); V loads
// from ONE base + literal offsets; K loads paired per address; shfl chains
// interleaved; s_setprio around MFMA clusters (T5).
__global__ __launch_bounds__(256, 3) void attn_kernel(const u16* __restrict__ qkv, const u16* __restrict__ vT,
                                                      const float* __restrict__ biasT,
                                                      float* __restrict__ out) {
  __shared__ u16 p_lds[32 * 512];            // 32 KB
  __shared__ float bias_lds[544];
  __shared__ float reds[4][32];

  const int flat = blockIdx.x;
  const int bh = ((flat >> 7) << 3) | (flat & 7);
  const int q0 = ((flat >> 3) & 15) * 32;
  const int b = bh >> 3, h = bh & 7;
  const int t = threadIdx.x, l = t & 63, w = t >> 6;
  const int lr = l & 15, lq = l >> 4;

  // bias slice (coalesced): bias for (q,key) = bias_lds[key + 31 - (q - q0)]
  {
    const int rel0 = 480 - q0;
    const float* bsrc = biasT + h * 1024 + rel0;
    for (int i = t; i < 543; i += 256)
      bias_lds[i] = bsrc[i];
  }

  // Q B-frags (pre-scaled by SCALE2 via cvt_w)
  bf16x8 bq[2][2];
#pragma unroll
  for (int qt = 0; qt < 2; ++qt) {
    const u16* qrow = qkv + (size_t)(b * 512 + q0 + qt * 16 + lr) * NQKV + h * 64;
    bq[qt][0] = *(const bf16x8*)(qrow + lq * 8);
    bq[qt][1] = *(const bf16x8*)(qrow + 32 + lq * 8);
  }

  // ---- phase 1: S^T = K Q^T (already exp2-domain) ----
  // 8 addresses, 2 pinned loads each (offset:0 / offset:64). One drain.
  const u16* kbase = qkv + (size_t)(b * 512 + w * 128 + lr) * NQKV + 512 + h * 64 + lq * 8;
  u32x4 akr[8][2];
#pragma unroll
  for (int ct = 0; ct < 8; ++ct) {
    const u16* kr = kbase + (size_t)ct * 16 * NQKV;
    asm volatile("global_load_dwordx4 %0, %2, off\n\t"
                 "global_load_dwordx4 %1, %2, off offset:64"
                 : "=&v"(akr[ct][0]), "=&v"(akr[ct][1]) : "v"(kr));
  }
  asm volatile("s_waitcnt vmcnt(0)" ::: "memory");
  __builtin_amdgcn_sched_barrier(0);           // rule #18: pin MFMAs after wait

  f32x4 sT[2][8];
  __builtin_amdgcn_s_setprio(1);
#pragma unroll
  for (int ct = 0; ct < 8; ++ct) {
    bf16x8 ak0 = __builtin_bit_cast(bf16x8, akr[ct][0]);
    bf16x8 ak1 = __builtin_bit_cast(bf16x8, akr[ct][1]);
    f32x4 a0 = {0.f, 0.f, 0.f, 0.f}, a1 = {0.f, 0.f, 0.f, 0.f};
    a0 = __builtin_amdgcn_mfma_f32_16x16x32_bf16(ak0, bq[0][0], a0, 0, 0, 0);
    a0 = __builtin_amdgcn_mfma_f32_16x16x32_bf16(ak1, bq[0][1], a0, 0, 0, 0);
    a1 = __builtin_amdgcn_mfma_f32_16x16x32_bf16(ak0, bq[1][0], a1, 0, 0, 0);
    a1 = __builtin_amdgcn_mfma_f32_16x16x32_bf16(ak1, bq[1][1], a1, 0, 0, 0);
    sT[0][ct] = a0;
    sT[1][ct] = a1;
  }
  __builtin_amdgcn_s_setprio(0);

  // exp2 + per-query sum; 4 partial accumulators per qt; the two qt shfl
  // chains interleaved to hide ds_bpermute latency.
  float sq[2];
#pragma unroll
  for (int qt = 0; qt < 2; ++qt) {
    float s0 = 0.f, s1 = 0.f, s2 = 0.f, s3 = 0.f;
#pragma unroll
    for (int ct = 0; ct < 8; ++ct) {
      float e0 = exp2f(sT[qt][ct][0]);
      float e1 = exp2f(sT[qt][ct][1]);
      float e2 = exp2f(sT[qt][ct][2]);
      float e3 = exp2f(sT[qt][ct][3]);
      sT[qt][ct][0] = e0; sT[qt][ct][1] = e1;
      sT[qt][ct][2] = e2; sT[qt][ct][3] = e3;
      s0 += e0; s1 += e1; s2 += e2; s3 += e3;
    }
    sq[qt] = (s0 + s1) + (s2 + s3);
  }
  {
    float t0 = sq[0], t1 = sq[1];
    float u0 = __shfl_xor(t0, 16, 64), u1 = __shfl_xor(t1, 16, 64);
    t0 += u0; t1 += u1;
    u0 = __shfl_xor(t0, 32, 64); u1 = __shfl_xor(t1, 32, 64);
    sq[0] = t0 + u0; sq[1] = t1 + u1;
  }
  if (lq == 0) { reds[w][lr] = sq[0]; reds[w][16 + lr] = sq[1]; }
  __syncthreads();                                         // barrier 1
  float rinv[2];
#pragma unroll
  for (int qt = 0; qt < 2; ++qt)
    rinv[qt] = 1.0f / (reds[0][qt * 16 + lr] + reds[1][qt * 16 + lr] +
                       reds[2][qt * 16 + lr] + reds[3][qt * 16 + lr]);

  // ---- V preload (pinned asm): ONE base address, literal offsets 0..960.
  // Split 8+8 around qt=0's pack to bound peak regs; barrier 2 drains free.
  const u16* vrow = vT + (size_t)(bh * 64 + w * 16 + lr) * 512 + lq * 8;
  u32x4 avr[16];
#define GLV(i, o0, o1)                                                         \
  asm volatile("global_load_dwordx4 %0, %2, off offset:" o0 "\n\t"             \
               "global_load_dwordx4 %1, %2, off offset:" o1                    \
               : "=&v"(avr[i]), "=&v"(avr[(i) + 1]) : "v"(vrow))
  GLV(0, "0", "64"); GLV(2, "128", "192"); GLV(4, "256", "320"); GLV(6, "384", "448");

  // ---- pack P = e*rinv + bias -> bf16 LDS (swizzled b64 stores) ----
#define PACK_QT(qt)                                                            \
  {                                                                            \
    const int qlocal = (qt) * 16 + lr;                                         \
    u16* prow = p_lds + qlocal * 512;                                          \
    const int boff = w * 128 + lq * 4 + 31 - qlocal;                           \
    _Pragma("unroll")                                                          \
    for (int ct = 0; ct < 8; ++ct) {                                           \
      const int gsw = w * 8 + (ct ^ (lr & 7));                                 \
      float p0 = sT[qt][ct][0] * rinv[qt] + bias_lds[boff + ct * 16 + 0];      \
      float p1 = sT[qt][ct][1] * rinv[qt] + bias_lds[boff + ct * 16 + 1];      \
      float p2 = sT[qt][ct][2] * rinv[qt] + bias_lds[boff + ct * 16 + 2];      \
      float p3 = sT[qt][ct][3] * rinv[qt] + bias_lds[boff + ct * 16 + 3];      \
      uint2 pk; pk.x = pack2(p0, p1); pk.y = pack2(p2, p3);                    \
      *(uint2*)&prow[gsw * 16 + lq * 4] = pk;                                  \
    }                                                                          \
  }

  PACK_QT(0)
  GLV(8, "512", "576"); GLV(10, "640", "704"); GLV(12, "768", "832"); GLV(14, "896", "960");
#undef GLV
  PACK_QT(1)
#undef PACK_QT

  __syncthreads();                                         // barrier 2 (drains vmcnt)
  asm volatile("s_waitcnt vmcnt(0)" ::: "memory");         // belt + suspenders
  __builtin_amdgcn_sched_barrier(0);

  // ---- phase 3 (transposed): out^T(d,q) = V^T(d,k) P^T(k,q) ----
  // depth-4 software pipeline on the LDS P reads (ds_read ~120cy latency).
  f32x4 accP[2] = {};
  bf16x8 bp[4][2];
#define LDP(kb, qt) \
  (*(const bf16x8*)&p_lds[((qt) * 16 + lr) * 512 + \
    (((2 * (kb) + (lq >> 1)) & ~7) | (((2 * (kb) + (lq >> 1)) & 7) ^ (lr & 7))) * 16 + (lq & 1) * 8])
#pragma unroll
  for (int pre = 0; pre < 3; ++pre) { bp[pre][0] = LDP(pre, 0); bp[pre][1] = LDP(pre, 1); }
  __builtin_amdgcn_s_setprio(1);
#pragma unroll
  for (int kb = 0; kb < 16; ++kb) {
    if (kb < 13) {
      bp[(kb + 3) & 3][0] = LDP(kb + 3, 0);
      bp[(kb + 3) & 3][1] = LDP(kb + 3, 1);
    }
    bf16x8 av = __builtin_bit_cast(bf16x8, avr[kb]);
    accP[0] = __builtin_amdgcn_mfma_f32_16x16x32_bf16(av, bp[kb & 3][0], accP[0], 0, 0, 0);
    accP[1] = __builtin_amdgcn_mfma_f32_16x16x32_bf16(av, bp[kb & 3][1], accP[1], 0, 0, 0);
  }
  __builtin_amdgcn_s_setprio(0);
#undef LDP
  // D[m=d_off][n=q]: lane holds q = lr, d = w*16 + lq*4 + i  -> f32x4 store
#pragma unroll
  for (int qt = 0; qt < 2; ++qt)
    *(f32x4*)&out[(size_t)(b * 512 + q0 + qt * 16 + lr) * 512 + h * 64 + w * 16 + lq * 4] = accP[qt];
}

// ---------------- LayerNorm: 2 rows/block, float4 ----------------
__global__ __launch_bounds__(256) void ln_kernel(float* __restrict__ out,
                                                 const float* __restrict__ gamma,
                                                 const float* __restrict__ beta) {
  const int t = threadIdx.x;
  const int r2 = t >> 7;                       // row half: 0/1
  const int row = blockIdx.x * 2 + r2;
  const int c = (t & 127) * 4;
  float* p = out + (size_t)row * 512;
  float4 v = *(float4*)(p + c);
  float s = v.x + v.y + v.z + v.w;
  float s2 = v.x * v.x + v.y * v.y + v.z * v.z + v.w * v.w;
#pragma unroll
  for (int d = 1; d < 64; d <<= 1) { s += __shfl_xor(s, d, 64); s2 += __shfl_xor(s2, d, 64); }
  __shared__ float ps[4], ps2[4];
  const int wv = t >> 6;
  if ((t & 63) == 0) { ps[wv] = s; ps2[wv] = s2; }
  __syncthreads();
  s  = ps[r2 * 2]  + ps[r2 * 2 + 1];
  s2 = ps2[r2 * 2] + ps2[r2 * 2 + 1];
  float mu = s * (1.0f / 512.0f);
  float var = s2 * (1.0f / 512.0f) - mu * mu;
  float rs = rsqrtf(var + 1e-5f);
  float4 g = *(const float4*)(gamma + c);
  float4 bb = *(const float4*)(beta + c);
  v.x = g.x * (v.x - mu) * rs + bb.x;
  v.y = g.y * (v.y - mu) * rs + bb.y;
  v.z = g.z * (v.z - mu) * rs + bb.z;
  v.w = g.w * (v.w - mu) * rs + bb.w;
  *(float4*)(p + c) = v;
}

extern "C" void kernel_launch(void* const* d_in, const int* in_sizes, int n_in,
                              void* d_out, int out_size, void* d_ws, size_t ws_size,
                              hipStream_t stream) {
  const float* x    = (const float*)d_in[0];
  const float* wq   = (const float*)d_in[1];
  const float* wk   = (const float*)d_in[2];
  const float* wv   = (const float*)d_in[3];
  const float* bias = (const float*)d_in[4];
  const float* gamma = (const float*)d_in[5];
  const float* beta  = (const float*)d_in[6];
  float* out = (float*)d_out;

  char* ws = (char*)d_ws;
  u16* xb   = (u16*)ws;                       // x in bf16 (reused as vT afterwards)
  u16* wcat = (u16*)(ws + XB_BYTES);          // concat weights bf16 (wq pre-scaled)
  u16* qkv  = (u16*)(ws + QKV_OFF);           // MROWS x 1536 bf16
  u16* vT   = xb;                             // reuse: gemm done with xb before transpose
  float* biasT = (float*)(ws + XB_BYTES);     // reuse wcat region after gemm (8 x 1024 f32)

  cvt_x<<<dim3((MROWS * CC) / 4 / 256), 256, 0, stream>>>(x, xb);
  cvt_w<<<dim3((NQKV * CC) / 4 / 256), 256, 0, stream>>>(wq, wk, wv, wcat);
  gemm_qkv<<<dim3(NQKV / 128, MROWS / 128), 256, 0, stream>>>(xb, wcat, qkv);
  transpose_v<<<dim3(256, 5), 256, 0, stream>>>(qkv, vT, bias, biasT);
  attn_kernel<<<dim3(16 * 256), 256, 0, stream>>>(qkv, vT, biasT, out);
  ln_kernel<<<dim3(MROWS / 2), 256, 0, stream>>>(out, gamma, beta);
}

// Round 5
// 224.276 us; speedup vs baseline: 1.0385x; 1.0121x over previous
//
#include <hip/hip_runtime.h>
#include <hip/hip_bf16.h>

typedef unsigned short u16;
typedef __attribute__((ext_vector_type(8))) __bf16 bf16x8;
typedef __attribute__((ext_vector_type(4))) float f32x4;
typedef __attribute__((ext_vector_type(4))) unsigned int u32x4;

// Problem dims
#define BB 32
#define LL 512
#define CC 512
#define HH 8
#define DH 64
#define MROWS (BB * LL)        // 16384
#define NQKV  (3 * CC)         // 1536

// workspace layout (bytes)
#define XB_BYTES ((size_t)MROWS * CC * 2)        // 16,777,216  (x bf16; later reused as vT)
#define WC_BYTES ((size_t)NQKV * CC * 2)         //  1,572,864  (wq|wk|wv bf16; dead after gemm -> biasT)
#define QKV_OFF  (XB_BYTES + WC_BYTES)           // qkv bf16: MROWS x 1536

// softmax scale (512^-0.5) * log2(e), folded into wq at cvt time: QK^T MFMA
// output is already in the exp2 domain. No max-subtract needed (scores' std
// ~0.07, validated R4).
#define SCALE2 (0.044194173824159216f * 1.4426950408889634f)

#if __has_builtin(__builtin_amdgcn_exp2f)
#define EXP2(x) __builtin_amdgcn_exp2f(x)
#else
#define EXP2(x) exp2f(x)
#endif
#if __has_builtin(__builtin_amdgcn_rcpf)
#define RCP(x) __builtin_amdgcn_rcpf(x)
#else
#define RCP(x) (1.0f / (x))
#endif

__device__ inline u16 f2b(float f) {
  union { float f; unsigned u; } a; a.f = f;
  unsigned u = a.u;
  return (u16)((u + 0x7FFFu + ((u >> 16) & 1u)) >> 16);
}

__device__ inline unsigned pack2(float a, float b) {  // v_cvt_pk_bf16_f32
  float2 f; f.x = a; f.y = b;
  union { __hip_bfloat162 h; unsigned u; } c;
  c.h = __float22bfloat162_rn(f);
  return c.u;
}

// ---------------- conversion kernels ----------------
__global__ __launch_bounds__(256) void cvt_x(const float* __restrict__ x, u16* __restrict__ xb) {
  int i = blockIdx.x * 256 + threadIdx.x;       // one float4 per thread
  float4 v = ((const float4*)x)[i];
  uint2 o; o.x = pack2(v.x, v.y); o.y = pack2(v.z, v.w);
  ((uint2*)xb)[i] = o;
}

__global__ __launch_bounds__(256) void cvt_w(const float* __restrict__ wq, const float* __restrict__ wk,
                                             const float* __restrict__ wv, u16* __restrict__ wcat) {
  int i = blockIdx.x * 256 + threadIdx.x;       // one float4 per thread
  int e = i * 4;
  int n = e >> 9;                                // output row 0..1535
  int k = e & 511;
  const float* src = (n < 512) ? (wq + (size_t)n * 512)
                   : (n < 1024) ? (wk + (size_t)(n - 512) * 512)
                                : (wv + (size_t)(n - 1024) * 512);
  const float sc = (n < 512) ? SCALE2 : 1.0f;   // fold softmax scale into Q
  float4 v = *(const float4*)(src + k);
  uint2 o; o.x = pack2(v.x * sc, v.y * sc); o.y = pack2(v.z * sc, v.w * sc);
  *(uint2*)(wcat + (size_t)n * 512 + k) = o;
}

// ---------------- async global->LDS ----------------
typedef __attribute__((address_space(1))) void* as1_void_p;
typedef __attribute__((address_space(3))) void* as3_void_p;

__device__ inline void async16(const u16* g, u16* l) {
#if __has_builtin(__builtin_amdgcn_global_load_lds)
  __builtin_amdgcn_global_load_lds((as1_void_p)g, (as3_void_p)l, 16, 0, 0);
#else
  *(uint4*)l = *(const uint4*)g;
#endif
}

// ---------------- QKV projection GEMM (m97-style, unchanged) ----------------
__global__ __launch_bounds__(256) void gemm_qkv(const u16* __restrict__ A, const u16* __restrict__ Bw,
                                                u16* __restrict__ Cm) {
  __shared__ u16 a_lds[128 * 32];
  __shared__ u16 b_lds[128 * 32];
  const int n0 = blockIdx.x * 128, m0 = blockIdx.y * 128;
  const int t = threadIdx.x, l = t & 63;
  const int wrow = ((t >> 7) & 1) * 64, wcol = ((t >> 6) & 1) * 64;
  const int lr = l & 15, lq = l >> 4;

  f32x4 acc[4][4] = {};

  for (int k0 = 0; k0 < 512; k0 += 32) {
    {
      int c0 = t, c1 = t + 256;
      async16(A  + (size_t)(m0 + (c0 >> 2)) * 512 + k0 + (c0 & 3) * 8, &a_lds[c0 * 8]);
      async16(A  + (size_t)(m0 + (c1 >> 2)) * 512 + k0 + (c1 & 3) * 8, &a_lds[c1 * 8]);
      async16(Bw + (size_t)(n0 + (c0 >> 2)) * 512 + k0 + (c0 & 3) * 8, &b_lds[c0 * 8]);
      async16(Bw + (size_t)(n0 + (c1 >> 2)) * 512 + k0 + (c1 & 3) * 8, &b_lds[c1 * 8]);
    }
    __syncthreads();
    bf16x8 af[4], bfr[4];
#pragma unroll
    for (int r = 0; r < 4; ++r) af[r]  = *(const bf16x8*)&a_lds[(wrow + r * 16 + lr) * 32 + lq * 8];
#pragma unroll
    for (int c = 0; c < 4; ++c) bfr[c] = *(const bf16x8*)&b_lds[(wcol + c * 16 + lr) * 32 + lq * 8];
#pragma unroll
    for (int r = 0; r < 4; ++r)
#pragma unroll
      for (int c = 0; c < 4; ++c)
        acc[r][c] = __builtin_amdgcn_mfma_f32_16x16x32_bf16(af[r], bfr[c], acc[r][c], 0, 0, 0);
    __syncthreads();
  }
#pragma unroll
  for (int r = 0; r < 4; ++r) {
#pragma unroll
    for (int i = 0; i < 4; ++i) {
      int m = m0 + wrow + r * 16 + lq * 4 + i;
      u16* crow = Cm + (size_t)m * NQKV + n0 + wcol;
#pragma unroll
      for (int c = 0; c < 4; ++c)
        crow[c * 16 + lr] = f2b(acc[r][c][i]);
    }
  }
}

// ---------------- V transpose + bias transpose ----------------
// blockIdx.y < 4 : qkv V-part (b,l,h,d) -> vT[(b*8+h)*64+d][l]
// blockIdx.y == 4: bias_table[rel][h] -> biasT[h][rel] (only x<32 active)
__global__ __launch_bounds__(256) void transpose_v(const u16* __restrict__ qkv, u16* __restrict__ vT,
                                                   const float* __restrict__ bias_table,
                                                   float* __restrict__ biasT) {
  if (blockIdx.y == 4) {
    if (blockIdx.x < 32) {
      int i = blockIdx.x * 256 + threadIdx.x;   // coalesced read of 1023*8
      if (i < 1023 * 8) {
        float v = bias_table[i];
        int rel = i >> 3, hh = i & 7;
        biasT[hh * 1024 + rel] = v;
      }
    }
    return;
  }
  const int bh = blockIdx.x;
  const int b = bh >> 3, h = bh & 7;
  const int lc0 = blockIdx.y * 128;
  __shared__ u16 tile[32 * 72];
  const int t = threadIdx.x;
  for (int lc = lc0; lc < lc0 + 128; lc += 32) {
    int lrow = t >> 3, dcol = (t & 7) * 8;
    const u16* src = qkv + (size_t)(b * 512 + lc + lrow) * NQKV + 1024 + h * 64 + dcol;
    *(uint4*)&tile[lrow * 72 + dcol] = *(const uint4*)src;
    __syncthreads();
    int d = t >> 2, lp = (t & 3) * 8;
    union { ushort4 v4[2]; u16 s[8]; } tmp;
#pragma unroll
    for (int j = 0; j < 8; ++j) tmp.s[j] = tile[(lp + j) * 72 + d];
    *(uint4*)&vT[(size_t)(bh * 64 + d) * 512 + lc + lp] = *(uint4*)&tmp;
    __syncthreads();
  }
}

// ---------------- fused attention (R9: occupancy-first, ring loads) --------
// 256 thr / 4 waves / 32 queries. Wave w owns keys [w*128,+128) in phase 1 and
// d-tile [w*16,+16) in phase 3 (transposed: A=V, B=P -> f32x4 stores).
// R9 theory: R5-R8 showed per-wave ILP is not the lever; residency is
// (occupancy 28-37%, total unified regs ~190-260/wave). This round cuts peak
// register demand to ~<=128 total so 4 waves/SIMD fit (LDS 35840 allows 4
// blocks/CU): K loads depth-4 ring (32 regs in flight, counted vmcnt literals
// tied to the consumed regs), V loads depth-8 ring (32 regs) issued before the
// pack and carried ACROSS a raw lgkmcnt-only barrier (no vmcnt(0) drain).
// exp2f -> raw v_exp_f32 (libm fixup fat, no -ffast-math in harness);
// 1/x -> v_rcp_f32. setprio dropped (R8 net-negative).
__global__ __launch_bounds__(256, 4) void attn_kernel(const u16* __restrict__ qkv, const u16* __restrict__ vT,
                                                      const float* __restrict__ biasT,
                                                      float* __restrict__ out) {
  __shared__ u16 p_lds[32 * 512];            // 32 KB
  __shared__ float bias_lds[544];
  __shared__ float reds[4][32];

  const int flat = blockIdx.x;
  const int bh = ((flat >> 7) << 3) | (flat & 7);
  const int q0 = ((flat >> 3) & 15) * 32;
  const int b = bh >> 3, h = bh & 7;
  const int t = threadIdx.x, l = t & 63, w = t >> 6;
  const int lr = l & 15, lq = l >> 4;

  // bias slice (coalesced): bias for (q,key) = bias_lds[key + 31 - (q - q0)]
  {
    const int rel0 = 480 - q0;
    const float* bsrc = biasT + h * 1024 + rel0;
    for (int i = t; i < 543; i += 256)
      bias_lds[i] = bsrc[i];
  }
  // drain the bias-fill global loads so the counted K/V rings below see only
  // their own vmcnt traffic ("memory" also fences compiler load motion).
  asm volatile("s_waitcnt vmcnt(0)" ::: "memory");

  // Q B-frags (pre-scaled by SCALE2 via cvt_w); compiler-managed loads -- any
  // compiler-inserted wait before their first use is conservative vs the ring.
  bf16x8 bq[2][2];
#pragma unroll
  for (int qt = 0; qt < 2; ++qt) {
    const u16* qrow = qkv + (size_t)(b * 512 + q0 + qt * 16 + lr) * NQKV + h * 64;
    bq[qt][0] = *(const bf16x8*)(qrow + lq * 8);
    bq[qt][1] = *(const bf16x8*)(qrow + 32 + lq * 8);
  }

  // ---- phase 1: S^T = K Q^T (already exp2-domain), depth-4 K ring ----
  const u16* kbase = qkv + (size_t)(b * 512 + w * 128 + lr) * NQKV + 512 + h * 64 + lq * 8;
  u32x4 akr[4][2];
  f32x4 sT[2][8];

#define KISSUE(slot, ct) { const u16* kr = kbase + (size_t)(ct) * 16 * NQKV;   \
    asm volatile("global_load_dwordx4 %0, %2, off\n\t"                         \
                 "global_load_dwordx4 %1, %2, off offset:64"                   \
                 : "=&v"(akr[slot][0]), "=&v"(akr[slot][1]) : "v"(kr)); }
  // wait literal = 2 * (pairs issued after pair ct); tied outputs give the
  // MFMAs a data-dep through the wait (no sched_barrier needed, rule #18).
#define KSTEP(ct, lit, doissue) {                                              \
    if (doissue) KISSUE(((ct) + 3) & 3, (ct) + 3)                              \
    asm volatile("s_waitcnt vmcnt(" lit ")"                                    \
                 : "+v"(akr[(ct) & 3][0]), "+v"(akr[(ct) & 3][1]));            \
    bf16x8 ak0 = __builtin_bit_cast(bf16x8, akr[(ct) & 3][0]);                 \
    bf16x8 ak1 = __builtin_bit_cast(bf16x8, akr[(ct) & 3][1]);                 \
    f32x4 a0 = {0.f, 0.f, 0.f, 0.f}, a1 = {0.f, 0.f, 0.f, 0.f};                \
    a0 = __builtin_amdgcn_mfma_f32_16x16x32_bf16(ak0, bq[0][0], a0, 0, 0, 0);  \
    a0 = __builtin_amdgcn_mfma_f32_16x16x32_bf16(ak1, bq[0][1], a0, 0, 0, 0);  \
    a1 = __builtin_amdgcn_mfma_f32_16x16x32_bf16(ak0, bq[1][0], a1, 0, 0, 0);  \
    a1 = __builtin_amdgcn_mfma_f32_16x16x32_bf16(ak1, bq[1][1], a1, 0, 0, 0);  \
    sT[0][ct] = a0; sT[1][ct] = a1; }

  KISSUE(0, 0) KISSUE(1, 1) KISSUE(2, 2)
  KSTEP(0, "6", 1) KSTEP(1, "6", 1) KSTEP(2, "6", 1) KSTEP(3, "6", 1)
  KSTEP(4, "6", 1) KSTEP(5, "4", 0) KSTEP(6, "2", 0) KSTEP(7, "0", 0)
#undef KSTEP
#undef KISSUE

  // exp2 (raw v_exp_f32) + per-query sum; 4 partial accumulators per qt.
  float sq[2];
#pragma unroll
  for (int qt = 0; qt < 2; ++qt) {
    float s0 = 0.f, s1 = 0.f, s2 = 0.f, s3 = 0.f;
#pragma unroll
    for (int ct = 0; ct < 8; ++ct) {
      float e0 = EXP2(sT[qt][ct][0]);
      float e1 = EXP2(sT[qt][ct][1]);
      float e2 = EXP2(sT[qt][ct][2]);
      float e3 = EXP2(sT[qt][ct][3]);
      sT[qt][ct][0] = e0; sT[qt][ct][1] = e1;
      sT[qt][ct][2] = e2; sT[qt][ct][3] = e3;
      s0 += e0; s1 += e1; s2 += e2; s3 += e3;
    }
    sq[qt] = (s0 + s1) + (s2 + s3);
  }
  {
    float t0 = sq[0], t1 = sq[1];
    float u0 = __shfl_xor(t0, 16, 64), u1 = __shfl_xor(t1, 16, 64);
    t0 += u0; t1 += u1;
    u0 = __shfl_xor(t0, 32, 64); u1 = __shfl_xor(t1, 32, 64);
    sq[0] = t0 + u0; sq[1] = t1 + u1;
  }
  if (lq == 0) { reds[w][lr] = sq[0]; reds[w][16 + lr] = sq[1]; }

  // barrier 1: lgkm-only raw barrier (no global traffic to protect here).
  asm volatile("s_waitcnt lgkmcnt(0)" ::: "memory");
  __builtin_amdgcn_s_barrier();
  asm volatile("" ::: "memory");

  float rinv[2];
#pragma unroll
  for (int qt = 0; qt < 2; ++qt)
    rinv[qt] = RCP(reds[0][qt * 16 + lr] + reds[1][qt * 16 + lr] +
                   reds[2][qt * 16 + lr] + reds[3][qt * 16 + lr]);

  // ---- V ring: 8 slots (32 regs) issued BEFORE the pack; they stay in
  // flight across the raw barrier (no vmcnt drain) and land during phase 3.
  const u16* vrow = vT + (size_t)(bh * 64 + w * 16 + lr) * 512 + lq * 8;
  u32x4 avr[8];
#define VISSUE(slot, olit)                                                     \
  asm volatile("global_load_dwordx4 %0, %1, off offset:" olit                  \
               : "=&v"(avr[slot]) : "v"(vrow));
  VISSUE(0, "0")   VISSUE(1, "64")  VISSUE(2, "128") VISSUE(3, "192")
  VISSUE(4, "256") VISSUE(5, "320") VISSUE(6, "384") VISSUE(7, "448")

  // ---- pack P = e*rinv + bias -> bf16 LDS (swizzled b64 stores) ----
#define PACK_QT(qt)                                                            \
  {                                                                            \
    const int qlocal = (qt) * 16 + lr;                                         \
    u16* prow = p_lds + qlocal * 512;                                          \
    const int boff = w * 128 + lq * 4 + 31 - qlocal;                           \
    _Pragma("unroll")                                                          \
    for (int ct = 0; ct < 8; ++ct) {                                           \
      const int gsw = w * 8 + (ct ^ (lr & 7));                                 \
      float p0 = sT[qt][ct][0] * rinv[qt] + bias_lds[boff + ct * 16 + 0];      \
      float p1 = sT[qt][ct][1] * rinv[qt] + bias_lds[boff + ct * 16 + 1];      \
      float p2 = sT[qt][ct][2] * rinv[qt] + bias_lds[boff + ct * 16 + 2];      \
      float p3 = sT[qt][ct][3] * rinv[qt] + bias_lds[boff + ct * 16 + 3];      \
      uint2 pk; pk.x = pack2(p0, p1); pk.y = pack2(p2, p3);                    \
      *(uint2*)&prow[gsw * 16 + lq * 4] = pk;                                  \
    }                                                                          \
  }
  PACK_QT(0)
  PACK_QT(1)
#undef PACK_QT

  // barrier 2: lgkm-only raw barrier -- p_lds writes drained, V loads NOT.
  asm volatile("s_waitcnt lgkmcnt(0)" ::: "memory");
  __builtin_amdgcn_s_barrier();
  asm volatile("" ::: "memory");

  // ---- phase 3 (transposed): out^T(d,q) = V^T(d,k) P^T(k,q) ----
  // V ring continues: consume slot kb&7, issue key kb+8 into the same slot.
  // bp depth-2 pipeline on the LDS P reads (compiler-managed lgkmcnt).
  f32x4 accP[2] = {};
  bf16x8 bp[2][2];
#define LDP(kb, qt) \
  (*(const bf16x8*)&p_lds[((qt) * 16 + lr) * 512 + \
    (((2 * (kb) + (lq >> 1)) & ~7) | (((2 * (kb) + (lq >> 1)) & 7) ^ (lr & 7))) * 16 + (lq & 1) * 8])
  bp[0][0] = LDP(0, 0);
  bp[0][1] = LDP(0, 1);
#define PVSTEP(kb, lit, doissue, olit) {                                       \
    asm volatile("s_waitcnt vmcnt(" lit ")" : "+v"(avr[(kb) & 7]));            \
    if ((kb) < 15) {                                                           \
      bp[((kb) + 1) & 1][0] = LDP((kb) + 1, 0);                                \
      bp[((kb) + 1) & 1][1] = LDP((kb) + 1, 1);                                \
    }                                                                          \
    bf16x8 av = __builtin_bit_cast(bf16x8, avr[(kb) & 7]);                     \
    accP[0] = __builtin_amdgcn_mfma_f32_16x16x32_bf16(av, bp[(kb) & 1][0], accP[0], 0, 0, 0); \
    accP[1] = __builtin_amdgcn_mfma_f32_16x16x32_bf16(av, bp[(kb) & 1][1], accP[1], 0, 0, 0); \
    if (doissue) VISSUE((kb) & 7, olit) }
  PVSTEP(0,  "7", 1, "512") PVSTEP(1,  "7", 1, "576")
  PVSTEP(2,  "7", 1, "640") PVSTEP(3,  "7", 1, "704")
  PVSTEP(4,  "7", 1, "768") PVSTEP(5,  "7", 1, "832")
  PVSTEP(6,  "7", 1, "896") PVSTEP(7,  "7", 1, "960")
  PVSTEP(8,  "7", 0, "0")   PVSTEP(9,  "6", 0, "0")
  PVSTEP(10, "5", 0, "0")   PVSTEP(11, "4", 0, "0")
  PVSTEP(12, "3", 0, "0")   PVSTEP(13, "2", 0, "0")
  PVSTEP(14, "1", 0, "0")   PVSTEP(15, "0", 0, "0")
#undef PVSTEP
#undef VISSUE
#undef LDP
  // D[m=d_off][n=q]: lane holds q = lr, d = w*16 + lq*4 + i  -> f32x4 store
#pragma unroll
  for (int qt = 0; qt < 2; ++qt)
    *(f32x4*)&out[(size_t)(b * 512 + q0 + qt * 16 + lr) * 512 + h * 64 + w * 16 + lq * 4] = accP[qt];
}

// ---------------- LayerNorm: 2 rows/block, float4 ----------------
__global__ __launch_bounds__(256) void ln_kernel(float* __restrict__ out,
                                                 const float* __restrict__ gamma,
                                                 const float* __restrict__ beta) {
  const int t = threadIdx.x;
  const int r2 = t >> 7;                       // row half: 0/1
  const int row = blockIdx.x * 2 + r2;
  const int c = (t & 127) * 4;
  float* p = out + (size_t)row * 512;
  float4 v = *(float4*)(p + c);
  float s = v.x + v.y + v.z + v.w;
  float s2 = v.x * v.x + v.y * v.y + v.z * v.z + v.w * v.w;
#pragma unroll
  for (int d = 1; d < 64; d <<= 1) { s += __shfl_xor(s, d, 64); s2 += __shfl_xor(s2, d, 64); }
  __shared__ float ps[4], ps2[4];
  const int wv = t >> 6;
  if ((t & 63) == 0) { ps[wv] = s; ps2[wv] = s2; }
  __syncthreads();
  s  = ps[r2 * 2]  + ps[r2 * 2 + 1];
  s2 = ps2[r2 * 2] + ps2[r2 * 2 + 1];
  float mu = s * (1.0f / 512.0f);
  float var = s2 * (1.0f / 512.0f) - mu * mu;
  float rs = rsqrtf(var + 1e-5f);
  float4 g = *(const float4*)(gamma + c);
  float4 bb = *(const float4*)(beta + c);
  v.x = g.x * (v.x - mu) * rs + bb.x;
  v.y = g.y * (v.y - mu) * rs + bb.y;
  v.z = g.z * (v.z - mu) * rs + bb.z;
  v.w = g.w * (v.w - mu) * rs + bb.w;
  *(float4*)(p + c) = v;
}

extern "C" void kernel_launch(void* const* d_in, const int* in_sizes, int n_in,
                              void* d_out, int out_size, void* d_ws, size_t ws_size,
                              hipStream_t stream) {
  const float* x    = (const float*)d_in[0];
  const float* wq   = (const float*)d_in[1];
  const float* wk   = (const float*)d_in[2];
  const float* wv   = (const float*)d_in[3];
  const float* bias = (const float*)d_in[4];
  const float* gamma = (const float*)d_in[5];
  const float* beta  = (const float*)d_in[6];
  float* out = (float*)d_out;

  char* ws = (char*)d_ws;
  u16* xb   = (u16*)ws;                       // x in bf16 (reused as vT afterwards)
  u16* wcat = (u16*)(ws + XB_BYTES);          // concat weights bf16 (wq pre-scaled)
  u16* qkv  = (u16*)(ws + QKV_OFF);           // MROWS x 1536 bf16
  u16* vT   = xb;                             // reuse: gemm done with xb before transpose
  float* biasT = (float*)(ws + XB_BYTES);     // reuse wcat region after gemm (8 x 1024 f32)

  cvt_x<<<dim3((MROWS * CC) / 4 / 256), 256, 0, stream>>>(x, xb);
  cvt_w<<<dim3((NQKV * CC) / 4 / 256), 256, 0, stream>>>(wq, wk, wv, wcat);
  gemm_qkv<<<dim3(NQKV / 128, MROWS / 128), 256, 0, stream>>>(xb, wcat, qkv);
  transpose_v<<<dim3(256, 5), 256, 0, stream>>>(qkv, vT, bias, biasT);
  attn_kernel<<<dim3(16 * 256), 256, 0, stream>>>(qkv, vT, biasT, out);
  ln_kernel<<<dim3(MROWS / 2), 256, 0, stream>>>(out, gamma, beta);
}